// Round 2
// baseline (107177.759 us; speedup 1.0000x reference)
//
#include <hip/hip_runtime.h>
#include <hip/hip_fp16.h>

typedef float v4 __attribute__((ext_vector_type(4)));
typedef float f32x4 __attribute__((ext_vector_type(4)));
typedef _Float16 f16x8 __attribute__((ext_vector_type(8)));

#define ROWF 12
#define CHF  96
#define BASE 12
#define SHF  36880            // total LDS in f32 (147.5 KB)

// ---- recurrent-phase LDS map (f32 offsets; all regions alias the phase-A slot area,
//      written only after phase A finishes) ----
#define DUMP0   0             // gate dump: 48 frags * 256 f32 = 12288
#define PL_HI0  12352         // f16 planes: [49 pix][168 ch] per plane (4116 f32 each)
#define PL_LO0  16468
#define PL_HI1  20584
#define PL_LO1  24700         // plane(s): hi = PL_HI0 + s*8232, lo = PL_LO0 + s*8232
#define HF_OFF  28820         // h1 as f32: [2][49*64]
#define LG_OFF  35092         // logits [2][64]
#define PR_OFF  35220         // preds [2]
#define STATG   12588         // phase-A static staging: 49*257 f32 (12593)
#define PSTR    168           // f16 per pixel (21 granules, odd -> bank spread)
// plane channel map: h0:0..63  vp2:64  vp1:65  zeros:66..95  h1:96..159  pad:160..167
#define ZB_BYTE (PL_HI0*4 + 320)  // 16B of persistent zeros (pixel0 pad of hi_s0)

__device__ __forceinline__ float sigmoidf_(float v) { return 1.0f / (1.0f + expf(-v)); }

__device__ __forceinline__ void load_row12(const float* rb, float* rr) {
    v4 t0 = *(const v4*)(rb);
    v4 t1 = *(const v4*)(rb + 4);
    v4 t2 = *(const v4*)(rb + 8);
    rr[0] = t0[0]; rr[1] = t0[1]; rr[2]  = t0[2]; rr[3]  = t0[3];
    rr[4] = t1[0]; rr[5] = t1[1]; rr[6]  = t1[2]; rr[7]  = t1[3];
    rr[8] = t2[0]; rr[9] = t2[1]; rr[10] = t2[2]; rr[11] = t2[3];
}

// fp32 VALU gates conv (phase-A static only). Weights v4 [ic][tap][c][4g].
__device__ __forceinline__ void conv_gates(const float* SH, const v4* wbase, int nic,
                                           int slot0, int row,
                                           float* a0, float* a1, float* a2, float* a3)
{
    for (int ic = 0; ic < nic; ++ic) {
        const float* rb = &SH[BASE + (slot0 + ic) * CHF + (row - 1) * ROWF];
        float rr0[12], rr1[12], rr2[12];
        load_row12(rb, rr0);
        load_row12(rb + ROWF, rr1);
        load_row12(rb + 2 * ROWF, rr2);
        const v4* wp = wbase + (size_t)ic * 576;
        #pragma unroll
        for (int dy = 0; dy < 3; ++dy) {
            const float* rr = (dy == 0) ? rr0 : (dy == 1) ? rr1 : rr2;
            #pragma unroll
            for (int dx = 0; dx < 3; ++dx) {
                v4 w = wp[(dy * 3 + dx) * 64];
                #pragma unroll
                for (int cc = 0; cc < 7; ++cc) {
                    float in = rr[cc + dx];
                    a0[cc] = fmaf(w[0], in, a0[cc]);
                    a1[cc] = fmaf(w[1], in, a1[cc]);
                    a2[cc] = fmaf(w[2], in, a2[cc]);
                    a3[cc] = fmaf(w[3], in, a3[cc]);
                }
            }
        }
    }
}

// fp32 VALU feature conv (phase A conv0/conv1). Weights [ic][tap][OC].
__device__ __forceinline__ void conv_feat(const float* SH, const float* w, int nic,
                                          int slot0, int oc, int OC, int r0,
                                          float* a0, float* a1)
{
    for (int ic = 0; ic < nic; ++ic) {
        const float* rb = &SH[BASE + (slot0 + ic) * CHF + (r0 - 1) * ROWF];
        float rr0[12], rr1[12], rr2[12], rr3[12];
        load_row12(rb, rr0);
        load_row12(rb + ROWF, rr1);
        load_row12(rb + 2 * ROWF, rr2);
        load_row12(rb + 3 * ROWF, rr3);
        const float* wp = w + (size_t)ic * 9 * OC + oc;
        #pragma unroll
        for (int dy = 0; dy < 3; ++dy) {
            const float* ra  = (dy == 0) ? rr0 : (dy == 1) ? rr1 : rr2;
            const float* rb2 = (dy == 0) ? rr1 : (dy == 1) ? rr2 : rr3;
            #pragma unroll
            for (int dx = 0; dx < 3; ++dx) {
                float wv = wp[(dy * 3 + dx) * OC];
                #pragma unroll
                for (int cc = 0; cc < 7; ++cc) {
                    a0[cc] = fmaf(wv, ra[cc + dx],  a0[cc]);
                    a1[cc] = fmaf(wv, rb2[cc + dx], a1[cc]);
                }
            }
        }
    }
}

// LSTM epilogue via LDS dump (3 rounds over the 7 N-tiles = cols 0..111, live 0..97)
__device__ __forceinline__ void dump_epilogue(
    float* SH, f32x4 acc[4][4], int tid, int lane, int mg, int NT0, int NTN,
    float* cst, int chBase, bool wrH1f)
{
    #pragma unroll
    for (int r = 0; r < 3; ++r) {
        // write this round's fragments
        for (int i = 0; i < 4; ++i)
            for (int n = 0; n < NTN; ++n) {
                int ntg = NT0 + n;
                if (ntg >= 3 * r && ntg < 3 * r + 3) {
                    int slot = (ntg - 3 * r) * 16 + (mg * 4 + i);
                    *(f32x4*)&SH[DUMP0 + slot * 256 + lane * 4] = acc[i][n];
                }
            }
        __syncthreads();
        const int jmax = (r < 2) ? 6 : 2;
        for (int j = 0; j < jmax; ++j) {
            int e = tid + j * 512;
            int colr = e >> 6, ch = e & 63;
            int colg = 48 * r + colr;
            if (colg < 98) {
                float gv[4];
                #pragma unroll
                for (int g = 0; g < 4; ++g) {
                    int slot  = (colr >> 4) * 16 + g * 4 + (ch >> 4);
                    int laneD = (colg & 15) | (((ch >> 2) & 3) << 4);
                    gv[g] = SH[DUMP0 + slot * 256 + laneD * 4 + (ch & 3)];
                }
                float cOld = cst[r * 6 + j];
                float ig = sigmoidf_(gv[0]);
                float fg = sigmoidf_(gv[1]);
                float gg = tanhf(gv[2]);
                float og = sigmoidf_(gv[3]);
                float cy = fg * cOld + ig * gg;
                cst[r * 6 + j] = cy;
                float hy = og * tanhf(cy);
                int s = colg >= 49 ? 1 : 0, p = colg - 49 * s;
                _Float16* H = (_Float16*)((char*)SH + (size_t)(PL_HI0 + s * 8232) * 4);
                _Float16* L = (_Float16*)((char*)SH + (size_t)(PL_LO0 + s * 8232) * 4);
                _Float16 hv = (_Float16)hy;
                H[p * PSTR + chBase + ch] = hv;
                L[p * PSTR + chBase + ch] = (_Float16)(hy - (float)hv);
                if (wrH1f) SH[HF_OFF + s * 3136 + p * 64 + ch] = hy;
            }
        }
        __syncthreads();   // dump region reusable / plane writes visible
    }
}

extern "C" __global__ __launch_bounds__(512, 2)
void poly_rnn_main(const float* __restrict__ x,
                   const int*   __restrict__ firstv,
                   const float* __restrict__ w_c0, const float* __restrict__ b_c0,
                   const float* __restrict__ w_c1, const float* __restrict__ b_c1,
                   const float* __restrict__ w_s0,
                   const float* __restrict__ cx0b, const float* __restrict__ ch0b,
                   const _Float16* __restrict__ g0hi, const _Float16* __restrict__ g0lo,
                   const _Float16* __restrict__ g1hi, const _Float16* __restrict__ g1lo,
                   const float* __restrict__ cx1b, const float* __restrict__ ch1b,
                   const float* __restrict__ fcw,  const float* __restrict__ fcb,
                   float* __restrict__ out)
{
    extern __shared__ float SH[];
    const int tid = threadIdx.x;
    const int blk = blockIdx.x;
    const int lane = tid & 63, wv_ = tid >> 6;
    const int q = lane >> 4, l15 = lane & 15;
    const int mg = wv_ & 3, ng = wv_ >> 2;
    const int NT0 = ng ? 4 : 0, NTN = ng ? 3 : 4;

    for (int i = tid; i < SHF; i += 512) SH[i] = 0.f;
    __syncthreads();

    // ================= PHASE A (fp32 VALU, per sample) =================
    f32x4 st[4][4];                       // static gates0 (conv(x_feat,v_first)+biases)
    #pragma unroll
    for (int i = 0; i < 4; ++i)
        #pragma unroll
        for (int n = 0; n < 4; ++n) { st[i][n][0]=0.f; st[i][n][1]=0.f; st[i][n][2]=0.f; st[i][n][3]=0.f; }

    const int c6 = tid & 63, pg6 = tid >> 6;
    const float bi0 = cx0b[c6]        + ch0b[c6];
    const float bf0 = cx0b[64 + c6]   + ch0b[64 + c6];
    const float bg0 = cx0b[128 + c6]  + ch0b[128 + c6];
    const float bo0 = cx0b[192 + c6]  + ch0b[192 + c6];

    for (int s = 0; s < 2; ++s) {
        // stage x sample
        const float* xs = x + (size_t)(2 * blk + s) * (256 * 49);
        for (int i = tid; i < 256 * 49; i += 512) {
            int ch = i / 49, p = i % 49;
            SH[BASE + ch * CHF + (p / 7) * ROWF + 1 + (p % 7)] = xs[i];
        }
        __syncthreads();
        // conv0 + relu: slots 0..255 -> 256..383
        {
            const int oc = tid & 127, pg = tid >> 7;
            const int r0 = 2 * pg;
            float a0[7] = {0,0,0,0,0,0,0}, a1[7] = {0,0,0,0,0,0,0};
            conv_feat(SH, w_c0, 256, 0, oc, 128, r0, a0, a1);
            float b = b_c0[oc];
            float* ob = &SH[BASE + (256 + oc) * CHF];
            #pragma unroll
            for (int cc = 0; cc < 7; ++cc) ob[r0 * ROWF + 1 + cc] = fmaxf(a0[cc] + b, 0.f);
            if (pg < 3) {
                #pragma unroll
                for (int cc = 0; cc < 7; ++cc) ob[(r0 + 1) * ROWF + 1 + cc] = fmaxf(a1[cc] + b, 0.f);
            }
        }
        __syncthreads();
        // conv1 + relu: slots 256..383 -> 0..127 (x_feat)
        {
            const int oc = tid & 127, pg = tid >> 7;
            const int r0 = 2 * pg;
            float a0[7] = {0,0,0,0,0,0,0}, a1[7] = {0,0,0,0,0,0,0};
            conv_feat(SH, w_c1, 128, 256, oc, 128, r0, a0, a1);
            float b = b_c1[oc];
            float* ob = &SH[BASE + oc * CHF];
            #pragma unroll
            for (int cc = 0; cc < 7; ++cc) ob[r0 * ROWF + 1 + cc] = fmaxf(a0[cc] + b, 0.f);
            if (pg < 3) {
                #pragma unroll
                for (int cc = 0; cc < 7; ++cc) ob[(r0 + 1) * ROWF + 1 + cc] = fmaxf(a1[cc] + b, 0.f);
            }
        }
        __syncthreads();
        // v slots 128..130: zero then set v_first (slot 130)
        for (int i = tid; i < 3 * CHF; i += 512) SH[BASE + 128 * CHF + i] = 0.f;
        __syncthreads();
        if (tid == 0) {
            int fv = firstv[2 * blk + s];
            SH[BASE + 130 * CHF + (fv / 7) * ROWF + 1 + (fv % 7)] = 1.f;
        }
        __syncthreads();
        // static gates conv (131 input ch) -> staging [49][257]
        if (pg6 < 7) {
            float a0[7], a1[7], a2[7], a3[7];
            #pragma unroll
            for (int cc = 0; cc < 7; ++cc) { a0[cc] = bi0; a1[cc] = bf0; a2[cc] = bg0; a3[cc] = bo0; }
            conv_gates(SH, ((const v4*)w_s0) + c6, 131, 0, pg6, a0, a1, a2, a3);
            #pragma unroll
            for (int cc = 0; cc < 7; ++cc) {
                int p = pg6 * 7 + cc;
                SH[STATG + p * 257 +       c6] = a0[cc];
                SH[STATG + p * 257 +  64 + c6] = a1[cc];
                SH[STATG + p * 257 + 128 + c6] = a2[cc];
                SH[STATG + p * 257 + 192 + c6] = a3[cc];
            }
        }
        __syncthreads();
        // route into MFMA C-layout registers (this sample's columns only)
        for (int i = 0; i < 4; ++i)
            for (int n = 0; n < NTN; ++n) {
                int colg = (NT0 + n) * 16 + l15;
                if (colg < 98 && ((colg < 49) == (s == 0))) {
                    int p = colg - 49 * s;
                    #pragma unroll
                    for (int r = 0; r < 4; ++r) {
                        int oc = (mg * 4 + i) * 16 + q * 4 + r;
                        st[i][n][r] = SH[STATG + p * 257 + oc];
                    }
                }
            }
        __syncthreads();
        // re-zero staging span (restores slot pads it clobbered)
        for (int i = tid; i < 12593; i += 512) SH[STATG + i] = 0.f;
        __syncthreads();
    }

    // ---- init planes / h1f / logits / preds; set vp1 = v_first ----
    for (int i = tid; i < (PR_OFF + 4 - PL_HI0); i += 512) SH[PL_HI0 + i] = 0.f;
    __syncthreads();
    if (tid < 2) {
        int fv = firstv[2 * blk + tid];
        _Float16* H = (_Float16*)((char*)SH + (size_t)(PL_HI0 + tid * 8232) * 4);
        H[fv * PSTR + 65] = (_Float16)1.f;
    }
    __syncthreads();

    // ---- per-Ntile geometry ----
    int okc_[4], py0_[4], px0_[4], hB_[4], lB_[4];
    for (int n = 0; n < 4; ++n) {
        int colg = (NT0 + n) * 16 + l15;
        int ok = colg < 98; okc_[n] = ok;
        int s = (colg >= 49) ? 1 : 0;
        int p = ok ? colg - 49 * s : 0;
        py0_[n] = p / 7; px0_[n] = p % 7;
        hB_[n] = (PL_HI0 + s * 8232) * 4;
        lB_[n] = (PL_LO0 + s * 8232) * 4;
    }

    float b1[4][4];
    #pragma unroll
    for (int i = 0; i < 4; ++i)
        #pragma unroll
        for (int r = 0; r < 4; ++r) {
            int oc = (mg * 4 + i) * 16 + q * 4 + r;
            b1[i][r] = cx1b[oc] + ch1b[oc];
        }

    float c0s[14], c1s[14];
    #pragma unroll
    for (int i = 0; i < 14; ++i) { c0s[i] = 0.f; c1s[i] = 0.f; }

    const char* SHb = (const char*)SH;
    float* outB = out + (size_t)(2 * blk) * 450;

    for (int t = 0; t < 9; ++t) {
        f32x4 acc[4][4];
        // ---------- layer-0 dynamic gates: K-window f16 ch 0..95 (h0 + vp2/vp1 + zeros) ----------
        for (int i = 0; i < 4; ++i)
            for (int n = 0; n < NTN; ++n) acc[i][n] = st[i][n];
        for (int tap = 0; tap < 9; ++tap) {
            int dy = tap / 3 - 1, dx = tap % 3 - 1;
            int bh[4], bl[4];
            for (int n = 0; n < NTN; ++n) {
                int py = py0_[n] + dy, px = px0_[n] + dx;
                int ok = okc_[n] && ((unsigned)py < 7u) && ((unsigned)px < 7u);
                int qb = (py * 7 + px) * (PSTR * 2);
                bh[n] = ok ? hB_[n] + qb : -1;
                bl[n] = ok ? lB_[n] + qb : -1;
            }
            for (int kc = 0; kc < 3; ++kc) {
                int kof = kc * 64 + q * 16;
                f16x8 Bh[4], Bl[4];
                for (int n = 0; n < NTN; ++n) {
                    Bh[n] = *(const f16x8*)(SHb + (bh[n] < 0 ? ZB_BYTE : bh[n] + kof));
                    Bl[n] = *(const f16x8*)(SHb + (bl[n] < 0 ? ZB_BYTE : bl[n] + kof));
                }
                for (int i = 0; i < 4; ++i) {
                    int frag = (((tap * 3 + kc) * 16 + (mg * 4 + i)) << 9) + lane * 8;
                    f16x8 Ah = *(const f16x8*)(g0hi + frag);
                    f16x8 Al = *(const f16x8*)(g0lo + frag);
                    for (int n = 0; n < NTN; ++n) {
                        acc[i][n] = __builtin_amdgcn_mfma_f32_16x16x32_f16(Al, Bh[n], acc[i][n], 0, 0, 0);
                        acc[i][n] = __builtin_amdgcn_mfma_f32_16x16x32_f16(Ah, Bl[n], acc[i][n], 0, 0, 0);
                        acc[i][n] = __builtin_amdgcn_mfma_f32_16x16x32_f16(Ah, Bh[n], acc[i][n], 0, 0, 0);
                    }
                }
            }
        }
        dump_epilogue(SH, acc, tid, lane, mg, NT0, NTN, c0s, 0, false);

        // ---------- layer-1 gates: K = [h0_new (f16 ch 0..63) | h1_old (96..159)] ----------
        for (int i = 0; i < 4; ++i)
            for (int n = 0; n < NTN; ++n) {
                acc[i][n][0] = b1[i][0]; acc[i][n][1] = b1[i][1];
                acc[i][n][2] = b1[i][2]; acc[i][n][3] = b1[i][3];
            }
        for (int tap = 0; tap < 9; ++tap) {
            int dy = tap / 3 - 1, dx = tap % 3 - 1;
            int bh[4], bl[4];
            for (int n = 0; n < NTN; ++n) {
                int py = py0_[n] + dy, px = px0_[n] + dx;
                int ok = okc_[n] && ((unsigned)py < 7u) && ((unsigned)px < 7u);
                int qb = (py * 7 + px) * (PSTR * 2);
                bh[n] = ok ? hB_[n] + qb : -1;
                bl[n] = ok ? lB_[n] + qb : -1;
            }
            const int kofs1[4] = {0, 64, 192, 256};
            for (int kc = 0; kc < 4; ++kc) {
                int kof = kofs1[kc] + q * 16;
                f16x8 Bh[4], Bl[4];
                for (int n = 0; n < NTN; ++n) {
                    Bh[n] = *(const f16x8*)(SHb + (bh[n] < 0 ? ZB_BYTE : bh[n] + kof));
                    Bl[n] = *(const f16x8*)(SHb + (bl[n] < 0 ? ZB_BYTE : bl[n] + kof));
                }
                for (int i = 0; i < 4; ++i) {
                    int frag = (((tap * 4 + kc) * 16 + (mg * 4 + i)) << 9) + lane * 8;
                    f16x8 Ah = *(const f16x8*)(g1hi + frag);
                    f16x8 Al = *(const f16x8*)(g1lo + frag);
                    for (int n = 0; n < NTN; ++n) {
                        acc[i][n] = __builtin_amdgcn_mfma_f32_16x16x32_f16(Al, Bh[n], acc[i][n], 0, 0, 0);
                        acc[i][n] = __builtin_amdgcn_mfma_f32_16x16x32_f16(Ah, Bl[n], acc[i][n], 0, 0, 0);
                        acc[i][n] = __builtin_amdgcn_mfma_f32_16x16x32_f16(Ah, Bh[n], acc[i][n], 0, 0, 0);
                    }
                }
            }
        }
        dump_epilogue(SH, acc, tid, lane, mg, NT0, NTN, c1s, 96, true);

        // ---------- fc (fp32 VALU over h1 f32 copy) ----------
        {
            int o = tid >> 2, qq = tid & 3;
            float accf = 0.f;
            if (o < 100) {
                int s = (o < 50) ? 0 : 1;
                int cls = o - 50 * s;
                const float* wr = fcw + (size_t)cls * 3136;
                for (int ch = qq * 16; ch < qq * 16 + 16; ++ch) {
                    const float* hp = &SH[HF_OFF + s * 3136 + ch];
                    const float* wc = wr + ch * 49;
                    #pragma unroll 7
                    for (int p = 0; p < 49; ++p) accf = fmaf(hp[p * 64], wc[p], accf);
                }
            }
            accf += __shfl_xor(accf, 1, 64);
            accf += __shfl_xor(accf, 2, 64);
            if (o < 100 && qq == 0) {
                int s = (o < 50) ? 0 : 1;
                int cls = o - 50 * s;
                SH[LG_OFF + s * 64 + cls] = accf + fcb[cls];
            }
        }
        __syncthreads();
        // ---------- argmax + output ----------
        if (wv_ < 2) {
            int s = wv_;
            float v = (lane < 50) ? SH[LG_OFF + s * 64 + lane] : -3.4e38f;
            if (lane < 50) outB[(size_t)s * 450 + t * 50 + lane] = v;
            int idx = lane;
            #pragma unroll
            for (int off = 1; off < 64; off <<= 1) {
                float ov = __shfl_xor(v, off, 64);
                int   oi = __shfl_xor(idx, off, 64);
                if (ov > v || (ov == v && oi < idx)) { v = ov; idx = oi; }
            }
            if (lane == 0) SH[PR_OFF + s] = (float)idx;
        }
        __syncthreads();
        // ---------- v map rotate (plane f16 ch 64/65) ----------
        if (tid < 98) {
            int s = tid / 49, p = tid % 49;
            _Float16* H = (_Float16*)((char*)SH + (size_t)(PL_HI0 + s * 8232) * 4);
            _Float16 old = H[p * PSTR + 65];
            int pred = (int)SH[PR_OFF + s];
            H[p * PSTR + 64] = old;
            H[p * PSTR + 65] = (_Float16)((p == pred) ? 1.f : 0.f);
        }
        __syncthreads();
    }
}

// ================= weight repack kernels =================
__global__ void repack_conv_k(const float* __restrict__ w, float* __restrict__ o, int IC, int OC) {
    int i = blockIdx.x * 256 + threadIdx.x;
    int total = OC * IC * 9;
    if (i >= total) return;
    int oc = i % OC; int r = i / OC; int t = r % 9; int ic = r / 9;
    o[i] = w[(size_t)(oc * IC + ic) * 9 + t];
}

__global__ void repack_cx_k(const float* __restrict__ wx, float* __restrict__ o) {
    int i = blockIdx.x * 256 + threadIdx.x;
    if (i >= 131 * 9 * 256) return;
    int g = i & 3; int r = i >> 2; int cc = r & 63; r >>= 6; int t = r % 9; int ic = r / 9;
    int oc = g * 64 + cc;
    o[i] = wx[((size_t)oc * 131 + ic) * 9 + t];
}

__global__ void repack_g0dyn_k(const float* __restrict__ ch0w, const float* __restrict__ cx0w,
                               _Float16* __restrict__ ohi, _Float16* __restrict__ olo) {
    int i = blockIdx.x * 256 + threadIdx.x;
    if (i >= 221184) return;
    int j = i & 7; int lane = (i >> 3) & 63; int mt = (i >> 9) & 15;
    int rest = i >> 13; int kc = rest % 3; int tap = rest / 3;
    int m = mt * 16 + (lane & 15);
    int k = kc * 32 + (lane >> 4) * 8 + j;
    float wv = 0.f;
    if (k < 64)       wv = ch0w[((size_t)m * 64 + k) * 9 + tap];
    else if (k == 64) wv = cx0w[((size_t)m * 131 + 128) * 9 + tap];
    else if (k == 65) wv = cx0w[((size_t)m * 131 + 129) * 9 + tap];
    _Float16 hv = (_Float16)wv;
    ohi[i] = hv;
    olo[i] = (_Float16)(wv - (float)hv);
}

__global__ void repack_g1_k(const float* __restrict__ cx1w, const float* __restrict__ ch1w,
                            _Float16* __restrict__ ohi, _Float16* __restrict__ olo) {
    int i = blockIdx.x * 256 + threadIdx.x;
    if (i >= 294912) return;
    int j = i & 7; int lane = (i >> 3) & 63; int mt = (i >> 9) & 15;
    int rest = i >> 13; int kc = rest & 3; int tap = rest >> 2;
    int m = mt * 16 + (lane & 15);
    int kk = (lane >> 4) * 8 + j;
    float wv;
    if (kc < 2) wv = cx1w[((size_t)m * 64 + kc * 32 + kk) * 9 + tap];
    else        wv = ch1w[((size_t)m * 64 + (kc - 2) * 32 + kk) * 9 + tap];
    _Float16 hv = (_Float16)wv;
    ohi[i] = hv;
    olo[i] = (_Float16)(wv - (float)hv);
}

extern "C" void kernel_launch(void* const* d_in, const int* in_sizes, int n_in,
                              void* d_out, int out_size, void* d_ws, size_t ws_size,
                              hipStream_t stream)
{
    const float* x     = (const float*)d_in[0];
    const int*   fv    = (const int*)  d_in[1];
    const float* c0w   = (const float*)d_in[2];
    const float* c0b   = (const float*)d_in[3];
    const float* c1w   = (const float*)d_in[4];
    const float* c1b   = (const float*)d_in[5];
    const float* cx0w  = (const float*)d_in[6];
    const float* cx0b  = (const float*)d_in[7];
    const float* ch0w  = (const float*)d_in[8];
    const float* ch0b  = (const float*)d_in[9];
    const float* cx1w  = (const float*)d_in[10];
    const float* cx1b  = (const float*)d_in[11];
    const float* ch1w  = (const float*)d_in[12];
    const float* ch1b  = (const float*)d_in[13];
    const float* fcw   = (const float*)d_in[14];
    const float* fcb   = (const float*)d_in[15];
    float* out = (float*)d_out;
    const int n = in_sizes[0] / (256 * 49);

    float* ws   = (float*)d_ws;
    float* w_c0 = ws;                    // 294912
    float* w_c1 = w_c0 + 294912;         // 147456
    float* w_s0 = w_c1 + 147456;         // 301824
    _Float16* g0hi = (_Float16*)(w_s0 + 301824);   // 221184 halves
    _Float16* g0lo = g0hi + 221184;
    _Float16* g1hi = g0lo + 221184;                // 294912 halves
    _Float16* g1lo = g1hi + 294912;

    repack_conv_k <<<(294912 + 255) / 256, 256, 0, stream>>>(c0w, w_c0, 256, 128);
    repack_conv_k <<<(147456 + 255) / 256, 256, 0, stream>>>(c1w, w_c1, 128, 128);
    repack_cx_k   <<<(301824 + 255) / 256, 256, 0, stream>>>(cx0w, w_s0);
    repack_g0dyn_k<<<(221184 + 255) / 256, 256, 0, stream>>>(ch0w, cx0w, g0hi, g0lo);
    repack_g1_k   <<<(294912 + 255) / 256, 256, 0, stream>>>(cx1w, ch1w, g1hi, g1lo);

    (void)hipFuncSetAttribute((const void*)poly_rnn_main,
                              hipFuncAttributeMaxDynamicSharedMemorySize, SHF * 4);
    poly_rnn_main<<<n / 2, 512, SHF * 4, stream>>>(x, fv, w_c0, c0b, w_c1, c1b,
                                                   w_s0, cx0b, ch0b,
                                                   g0hi, g0lo, g1hi, g1lo,
                                                   cx1b, ch1b, fcw, fcb, out);
}

// Round 3
// 10293.046 us; speedup vs baseline: 10.4126x; 10.4126x over previous
//
#include <hip/hip_runtime.h>
#include <hip/hip_fp16.h>

typedef float v4 __attribute__((ext_vector_type(4)));
typedef float f32x4 __attribute__((ext_vector_type(4)));
typedef _Float16 f16x8 __attribute__((ext_vector_type(8)));

#define ROWF 12
#define CHF  96
#define BASE 12
#define SHF  36880            // total LDS in f32 (147.5 KB)

// ---- recurrent-phase LDS map (f32 word offsets; aliases the phase-A slot area) ----
#define DUMP0   0             // gate dump: 48 slots * 272 words = 13056 (16 rows*17 + col swizzle)
#define PL_HI0  13056         // f16 planes: [49 pix][168 ch]; hi = PL_HI0 + s*8232
#define PL_LO0  17172         //             lo = PL_LO0 + s*8232
#define HF_OFF  29520         // h1 as f32: [2][49*64]
#define LG_OFF  35792         // logits [2][64]
#define PR_OFF  35920         // preds [2]
#define STATG   12588         // phase-A static staging: 49*257 f32 (aliases dead slots 131+)
#define PSTR    168           // f16 per pixel (21 granules)
// plane channel map: h0:0..63  vp2:64  vp1:65  zeros:66..95  h1:96..159  pad:160..167
#define ZB_BYTE (PL_HI0*4 + 320)  // 16B of persistent zeros (pad ch 160.. of hi_s0 pixel 0)

__device__ __forceinline__ float sigmoidf_(float v) { return 1.0f / (1.0f + expf(-v)); }

__device__ __forceinline__ void load_row12(const float* rb, float* rr) {
    v4 t0 = *(const v4*)(rb);
    v4 t1 = *(const v4*)(rb + 4);
    v4 t2 = *(const v4*)(rb + 8);
    rr[0] = t0[0]; rr[1] = t0[1]; rr[2]  = t0[2]; rr[3]  = t0[3];
    rr[4] = t1[0]; rr[5] = t1[1]; rr[6]  = t1[2]; rr[7]  = t1[3];
    rr[8] = t2[0]; rr[9] = t2[1]; rr[10] = t2[2]; rr[11] = t2[3];
}

// fp32 VALU gates conv (phase-A static only). Weights v4 [ic][tap][c][4g].
__device__ __forceinline__ void conv_gates(const float* SH, const v4* wbase, int nic,
                                           int slot0, int row,
                                           float* a0, float* a1, float* a2, float* a3)
{
    for (int ic = 0; ic < nic; ++ic) {
        const float* rb = &SH[BASE + (slot0 + ic) * CHF + (row - 1) * ROWF];
        float rr0[12], rr1[12], rr2[12];
        load_row12(rb, rr0);
        load_row12(rb + ROWF, rr1);
        load_row12(rb + 2 * ROWF, rr2);
        const v4* wp = wbase + (size_t)ic * 576;
        #pragma unroll
        for (int dy = 0; dy < 3; ++dy) {
            const float* rr = (dy == 0) ? rr0 : (dy == 1) ? rr1 : rr2;
            #pragma unroll
            for (int dx = 0; dx < 3; ++dx) {
                v4 w = wp[(dy * 3 + dx) * 64];
                #pragma unroll
                for (int cc = 0; cc < 7; ++cc) {
                    float in = rr[cc + dx];
                    a0[cc] = fmaf(w[0], in, a0[cc]);
                    a1[cc] = fmaf(w[1], in, a1[cc]);
                    a2[cc] = fmaf(w[2], in, a2[cc]);
                    a3[cc] = fmaf(w[3], in, a3[cc]);
                }
            }
        }
    }
}

// fp32 VALU feature conv (phase A conv0/conv1). Weights [ic][tap][OC].
__device__ __forceinline__ void conv_feat(const float* SH, const float* w, int nic,
                                          int slot0, int oc, int OC, int r0,
                                          float* a0, float* a1)
{
    for (int ic = 0; ic < nic; ++ic) {
        const float* rb = &SH[BASE + (slot0 + ic) * CHF + (r0 - 1) * ROWF];
        float rr0[12], rr1[12], rr2[12], rr3[12];
        load_row12(rb, rr0);
        load_row12(rb + ROWF, rr1);
        load_row12(rb + 2 * ROWF, rr2);
        load_row12(rb + 3 * ROWF, rr3);
        const float* wp = w + (size_t)ic * 9 * OC + oc;
        #pragma unroll
        for (int dy = 0; dy < 3; ++dy) {
            const float* ra  = (dy == 0) ? rr0 : (dy == 1) ? rr1 : rr2;
            const float* rb2 = (dy == 0) ? rr1 : (dy == 1) ? rr2 : rr3;
            #pragma unroll
            for (int dx = 0; dx < 3; ++dx) {
                float wv = wp[(dy * 3 + dx) * OC];
                #pragma unroll
                for (int cc = 0; cc < 7; ++cc) {
                    a0[cc] = fmaf(wv, ra[cc + dx],  a0[cc]);
                    a1[cc] = fmaf(wv, rb2[cc + dx], a1[cc]);
                }
            }
        }
    }
}

// LSTM epilogue via LDS dump. Dump layout: word = slot*272 + row*17 + col
// (row-pad 17 => transposed read lands on all 32 banks, 2-way = free).
__device__ __forceinline__ void dump_epilogue(
    float* SH, f32x4 (&acc)[4][4], int tid, int lane, int mg, int ng,
    float (&cst)[13], int chBase, bool wrH1f)
{
    const int q = lane >> 4, l15 = lane & 15;
    #pragma unroll
    for (int r = 0; r < 3; ++r) {
        #pragma unroll
        for (int i = 0; i < 4; ++i)
            #pragma unroll
            for (int n = 0; n < 4; ++n) {
                int ntg = ng * 4 + n;
                if (ntg >= 3 * r && ntg < 3 * r + 3) {
                    int slot = (ntg - 3 * r) * 16 + (mg * 4 + i);
                    #pragma unroll
                    for (int r4 = 0; r4 < 4; ++r4)
                        SH[DUMP0 + slot * 272 + (q * 4 + r4) * 17 + l15] = acc[i][n][r4];
                }
            }
        __syncthreads();
        const int jm = (r == 2) ? 1 : 6;
        #pragma unroll 6
        for (int j = 0; j < jm; ++j) {
            const int jg = r * 6 + j;            // compile-time after unroll
            int e = tid + jg * 512;
            int colg = e >> 6, ch = e & 63;
            if (colg < 98) {
                int colrT = (colg - 48 * r) >> 4;
                float gv[4];
                #pragma unroll
                for (int g = 0; g < 4; ++g) {
                    int slot = colrT * 16 + g * 4 + (ch >> 4);
                    gv[g] = SH[DUMP0 + slot * 272 + (ch & 15) * 17 + (colg & 15)];
                }
                float cOld = cst[jg];
                float ig = sigmoidf_(gv[0]);
                float fg = sigmoidf_(gv[1]);
                float gg = tanhf(gv[2]);
                float og = sigmoidf_(gv[3]);
                float cy = fg * cOld + ig * gg;
                cst[jg] = cy;
                float hy = og * tanhf(cy);
                int s = colg >= 49 ? 1 : 0, p = colg - 49 * s;
                _Float16* H = (_Float16*)((char*)SH + (size_t)(PL_HI0 + s * 8232) * 4);
                _Float16* L = (_Float16*)((char*)SH + (size_t)(PL_LO0 + s * 8232) * 4);
                _Float16 hv = (_Float16)hy;
                H[p * PSTR + chBase + ch] = hv;
                L[p * PSTR + chBase + ch] = (_Float16)(hy - (float)hv);
                if (wrH1f) SH[HF_OFF + s * 3136 + p * 64 + ch] = hy;
            }
        }
        __syncthreads();
    }
}

extern "C" __global__ __launch_bounds__(512, 2)
void poly_rnn_main(const float* __restrict__ x,
                   const int*   __restrict__ firstv,
                   const float* __restrict__ w_c0, const float* __restrict__ b_c0,
                   const float* __restrict__ w_c1, const float* __restrict__ b_c1,
                   const float* __restrict__ w_s0,
                   const float* __restrict__ cx0b, const float* __restrict__ ch0b,
                   const _Float16* __restrict__ g0hi, const _Float16* __restrict__ g0lo,
                   const _Float16* __restrict__ g1hi, const _Float16* __restrict__ g1lo,
                   const float* __restrict__ cx1b, const float* __restrict__ ch1b,
                   const float* __restrict__ fcw,  const float* __restrict__ fcb,
                   float* __restrict__ out)
{
    extern __shared__ float SH[];
    const int tid = threadIdx.x;
    const int blk = blockIdx.x;
    const int lane = tid & 63, wv_ = tid >> 6;
    const int q = lane >> 4, l15 = lane & 15;
    const int mg = wv_ & 3, ng = wv_ >> 2;

    for (int i = tid; i < SHF; i += 512) SH[i] = 0.f;
    __syncthreads();

    // ================= PHASE A (fp32 VALU, per sample) =================
    f32x4 st[4][4];                       // static gates0 (conv(x_feat,v_first)+biases)
    #pragma unroll
    for (int i = 0; i < 4; ++i)
        #pragma unroll
        for (int n = 0; n < 4; ++n) { st[i][n][0]=0.f; st[i][n][1]=0.f; st[i][n][2]=0.f; st[i][n][3]=0.f; }

    const int c6 = tid & 63, pg6 = tid >> 6;
    const float bi0 = cx0b[c6]        + ch0b[c6];
    const float bf0 = cx0b[64 + c6]   + ch0b[64 + c6];
    const float bg0 = cx0b[128 + c6]  + ch0b[128 + c6];
    const float bo0 = cx0b[192 + c6]  + ch0b[192 + c6];

    for (int s = 0; s < 2; ++s) {
        const float* xs = x + (size_t)(2 * blk + s) * (256 * 49);
        for (int i = tid; i < 256 * 49; i += 512) {
            int ch = i / 49, p = i % 49;
            SH[BASE + ch * CHF + (p / 7) * ROWF + 1 + (p % 7)] = xs[i];
        }
        __syncthreads();
        // conv0 + relu: slots 0..255 -> 256..383
        {
            const int oc = tid & 127, pg = tid >> 7;
            const int r0 = 2 * pg;
            float a0[7] = {0,0,0,0,0,0,0}, a1[7] = {0,0,0,0,0,0,0};
            conv_feat(SH, w_c0, 256, 0, oc, 128, r0, a0, a1);
            float b = b_c0[oc];
            float* ob = &SH[BASE + (256 + oc) * CHF];
            #pragma unroll
            for (int cc = 0; cc < 7; ++cc) ob[r0 * ROWF + 1 + cc] = fmaxf(a0[cc] + b, 0.f);
            if (pg < 3) {
                #pragma unroll
                for (int cc = 0; cc < 7; ++cc) ob[(r0 + 1) * ROWF + 1 + cc] = fmaxf(a1[cc] + b, 0.f);
            }
        }
        __syncthreads();
        // conv1 + relu: slots 256..383 -> 0..127 (x_feat)
        {
            const int oc = tid & 127, pg = tid >> 7;
            const int r0 = 2 * pg;
            float a0[7] = {0,0,0,0,0,0,0}, a1[7] = {0,0,0,0,0,0,0};
            conv_feat(SH, w_c1, 128, 256, oc, 128, r0, a0, a1);
            float b = b_c1[oc];
            float* ob = &SH[BASE + oc * CHF];
            #pragma unroll
            for (int cc = 0; cc < 7; ++cc) ob[r0 * ROWF + 1 + cc] = fmaxf(a0[cc] + b, 0.f);
            if (pg < 3) {
                #pragma unroll
                for (int cc = 0; cc < 7; ++cc) ob[(r0 + 1) * ROWF + 1 + cc] = fmaxf(a1[cc] + b, 0.f);
            }
        }
        __syncthreads();
        // v slots 128..130: zero then set v_first (slot 130)
        for (int i = tid; i < 3 * CHF; i += 512) SH[BASE + 128 * CHF + i] = 0.f;
        __syncthreads();
        if (tid == 0) {
            int fv = firstv[2 * blk + s];
            SH[BASE + 130 * CHF + (fv / 7) * ROWF + 1 + (fv % 7)] = 1.f;
        }
        __syncthreads();
        // static gates conv (131 input ch) -> staging [49][257]
        if (pg6 < 7) {
            float a0[7], a1[7], a2[7], a3[7];
            #pragma unroll
            for (int cc = 0; cc < 7; ++cc) { a0[cc] = bi0; a1[cc] = bf0; a2[cc] = bg0; a3[cc] = bo0; }
            conv_gates(SH, ((const v4*)w_s0) + c6, 131, 0, pg6, a0, a1, a2, a3);
            #pragma unroll
            for (int cc = 0; cc < 7; ++cc) {
                int p = pg6 * 7 + cc;
                SH[STATG + p * 257 +       c6] = a0[cc];
                SH[STATG + p * 257 +  64 + c6] = a1[cc];
                SH[STATG + p * 257 + 128 + c6] = a2[cc];
                SH[STATG + p * 257 + 192 + c6] = a3[cc];
            }
        }
        __syncthreads();
        // route into MFMA C-layout registers (this sample's columns only)
        #pragma unroll
        for (int i = 0; i < 4; ++i)
            #pragma unroll
            for (int n = 0; n < 4; ++n) {
                int colg = ng * 64 + n * 16 + l15;
                if (colg < 98 && ((colg < 49) == (s == 0))) {
                    int p = colg - 49 * s;
                    #pragma unroll
                    for (int r = 0; r < 4; ++r) {
                        int oc = (mg * 4 + i) * 16 + q * 4 + r;
                        st[i][n][r] = SH[STATG + p * 257 + oc];
                    }
                }
            }
        __syncthreads();
        // re-zero staging span (restores slot pads it clobbered)
        for (int i = tid; i < 12593; i += 512) SH[STATG + i] = 0.f;
        __syncthreads();
    }

    // ---- init planes / h1f / logits / preds; set vp1 = v_first ----
    for (int i = tid; i < (PR_OFF + 4 - PL_HI0); i += 512) SH[PL_HI0 + i] = 0.f;
    __syncthreads();
    if (tid < 2) {
        int fv = firstv[2 * blk + tid];
        _Float16* H = (_Float16*)((char*)SH + (size_t)(PL_HI0 + tid * 8232) * 4);
        H[fv * PSTR + 65] = (_Float16)1.f;
    }
    __syncthreads();

    // ---- per-Ntile geometry (all unrolled -> registers) ----
    int okc_[4], py0_[4], px0_[4], hB_[4], lB_[4];
    #pragma unroll
    for (int n = 0; n < 4; ++n) {
        int colg = ng * 64 + n * 16 + l15;
        int ok = colg < 98; okc_[n] = ok;
        int s = (colg >= 49) ? 1 : 0;
        int p = ok ? colg - 49 * s : 0;
        py0_[n] = p / 7; px0_[n] = p % 7;
        hB_[n] = (PL_HI0 + s * 8232) * 4;
        lB_[n] = (PL_LO0 + s * 8232) * 4;
    }

    float b1[4][4];
    #pragma unroll
    for (int i = 0; i < 4; ++i)
        #pragma unroll
        for (int r = 0; r < 4; ++r) {
            int oc = (mg * 4 + i) * 16 + q * 4 + r;
            b1[i][r] = cx1b[oc] + ch1b[oc];
        }

    float c0s[13], c1s[13];
    #pragma unroll
    for (int i = 0; i < 13; ++i) { c0s[i] = 0.f; c1s[i] = 0.f; }

    const char* SHb = (const char*)SH;
    float* outB = out + (size_t)(2 * blk) * 450;

    for (int t = 0; t < 9; ++t) {
        f32x4 acc[4][4];
        // ---------- layer-0 dynamic gates: K-window f16 ch 0..95 ----------
        #pragma unroll
        for (int i = 0; i < 4; ++i)
            #pragma unroll
            for (int n = 0; n < 4; ++n) acc[i][n] = st[i][n];
        for (int tap = 0; tap < 9; ++tap) {
            int dy = tap / 3 - 1, dx = tap % 3 - 1;
            int bh[4], bl[4];
            #pragma unroll
            for (int n = 0; n < 4; ++n) {
                int py = py0_[n] + dy, px = px0_[n] + dx;
                int ok = okc_[n] && ((unsigned)py < 7u) && ((unsigned)px < 7u);
                int qb = (py * 7 + px) * (PSTR * 2);
                bh[n] = ok ? hB_[n] + qb : -1;
                bl[n] = ok ? lB_[n] + qb : -1;
            }
            #pragma unroll
            for (int kc = 0; kc < 3; ++kc) {
                int kof = kc * 64 + q * 16;
                f16x8 Bh[4], Bl[4];
                #pragma unroll
                for (int n = 0; n < 4; ++n) {
                    Bh[n] = *(const f16x8*)(SHb + (bh[n] < 0 ? ZB_BYTE : bh[n] + kof));
                    Bl[n] = *(const f16x8*)(SHb + (bl[n] < 0 ? ZB_BYTE : bl[n] + kof));
                }
                #pragma unroll
                for (int i = 0; i < 4; ++i) {
                    int frag = (((tap * 3 + kc) * 16 + (mg * 4 + i)) << 9) + lane * 8;
                    f16x8 Ah = *(const f16x8*)(g0hi + frag);
                    f16x8 Al = *(const f16x8*)(g0lo + frag);
                    #pragma unroll
                    for (int n = 0; n < 4; ++n) {
                        acc[i][n] = __builtin_amdgcn_mfma_f32_16x16x32_f16(Al, Bh[n], acc[i][n], 0, 0, 0);
                        acc[i][n] = __builtin_amdgcn_mfma_f32_16x16x32_f16(Ah, Bl[n], acc[i][n], 0, 0, 0);
                        acc[i][n] = __builtin_amdgcn_mfma_f32_16x16x32_f16(Ah, Bh[n], acc[i][n], 0, 0, 0);
                    }
                }
            }
        }
        dump_epilogue(SH, acc, tid, lane, mg, ng, c0s, 0, false);

        // ---------- layer-1 gates: K = [h0_new (ch 0..63) | h1_old (96..159)] ----------
        #pragma unroll
        for (int i = 0; i < 4; ++i)
            #pragma unroll
            for (int n = 0; n < 4; ++n) {
                acc[i][n][0] = b1[i][0]; acc[i][n][1] = b1[i][1];
                acc[i][n][2] = b1[i][2]; acc[i][n][3] = b1[i][3];
            }
        for (int tap = 0; tap < 9; ++tap) {
            int dy = tap / 3 - 1, dx = tap % 3 - 1;
            int bh[4], bl[4];
            #pragma unroll
            for (int n = 0; n < 4; ++n) {
                int py = py0_[n] + dy, px = px0_[n] + dx;
                int ok = okc_[n] && ((unsigned)py < 7u) && ((unsigned)px < 7u);
                int qb = (py * 7 + px) * (PSTR * 2);
                bh[n] = ok ? hB_[n] + qb : -1;
                bl[n] = ok ? lB_[n] + qb : -1;
            }
            #pragma unroll
            for (int kc = 0; kc < 4; ++kc) {
                const int kofs1 = (kc == 0) ? 0 : (kc == 1) ? 64 : (kc == 2) ? 192 : 256;
                int kof = kofs1 + q * 16;
                f16x8 Bh[4], Bl[4];
                #pragma unroll
                for (int n = 0; n < 4; ++n) {
                    Bh[n] = *(const f16x8*)(SHb + (bh[n] < 0 ? ZB_BYTE : bh[n] + kof));
                    Bl[n] = *(const f16x8*)(SHb + (bl[n] < 0 ? ZB_BYTE : bl[n] + kof));
                }
                #pragma unroll
                for (int i = 0; i < 4; ++i) {
                    int frag = (((tap * 4 + kc) * 16 + (mg * 4 + i)) << 9) + lane * 8;
                    f16x8 Ah = *(const f16x8*)(g1hi + frag);
                    f16x8 Al = *(const f16x8*)(g1lo + frag);
                    #pragma unroll
                    for (int n = 0; n < 4; ++n) {
                        acc[i][n] = __builtin_amdgcn_mfma_f32_16x16x32_f16(Al, Bh[n], acc[i][n], 0, 0, 0);
                        acc[i][n] = __builtin_amdgcn_mfma_f32_16x16x32_f16(Ah, Bl[n], acc[i][n], 0, 0, 0);
                        acc[i][n] = __builtin_amdgcn_mfma_f32_16x16x32_f16(Ah, Bh[n], acc[i][n], 0, 0, 0);
                    }
                }
            }
        }
        dump_epilogue(SH, acc, tid, lane, mg, ng, c1s, 96, true);

        // ---------- fc (fp32 VALU over h1 f32 copy) ----------
        {
            int o = tid >> 2, qq = tid & 3;
            float accf = 0.f;
            if (o < 100) {
                int s = (o < 50) ? 0 : 1;
                int cls = o - 50 * s;
                const float* wr = fcw + (size_t)cls * 3136;
                for (int ch = qq * 16; ch < qq * 16 + 16; ++ch) {
                    const float* hp = &SH[HF_OFF + s * 3136 + ch];
                    const float* wc = wr + ch * 49;
                    #pragma unroll 7
                    for (int p = 0; p < 49; ++p) accf = fmaf(hp[p * 64], wc[p], accf);
                }
            }
            accf += __shfl_xor(accf, 1, 64);
            accf += __shfl_xor(accf, 2, 64);
            if (o < 100 && qq == 0) {
                int s = (o < 50) ? 0 : 1;
                int cls = o - 50 * s;
                SH[LG_OFF + s * 64 + cls] = accf + fcb[cls];
            }
        }
        __syncthreads();
        // ---------- argmax + output ----------
        if (wv_ < 2) {
            int s = wv_;
            float v = (lane < 50) ? SH[LG_OFF + s * 64 + lane] : -3.4e38f;
            if (lane < 50) outB[(size_t)s * 450 + t * 50 + lane] = v;
            int idx = lane;
            #pragma unroll
            for (int off = 1; off < 64; off <<= 1) {
                float ov = __shfl_xor(v, off, 64);
                int   oi = __shfl_xor(idx, off, 64);
                if (ov > v || (ov == v && oi < idx)) { v = ov; idx = oi; }
            }
            if (lane == 0) SH[PR_OFF + s] = (float)idx;
        }
        __syncthreads();
        // ---------- v map rotate (plane f16 ch 64/65) ----------
        if (tid < 98) {
            int s = tid / 49, p = tid % 49;
            _Float16* H = (_Float16*)((char*)SH + (size_t)(PL_HI0 + s * 8232) * 4);
            _Float16 old = H[p * PSTR + 65];
            int pred = (int)SH[PR_OFF + s];
            H[p * PSTR + 64] = old;
            H[p * PSTR + 65] = (_Float16)((p == pred) ? 1.f : 0.f);
        }
        __syncthreads();
    }
}

// ================= weight repack kernels =================
__global__ void repack_conv_k(const float* __restrict__ w, float* __restrict__ o, int IC, int OC) {
    int i = blockIdx.x * 256 + threadIdx.x;
    int total = OC * IC * 9;
    if (i >= total) return;
    int oc = i % OC; int r = i / OC; int t = r % 9; int ic = r / 9;
    o[i] = w[(size_t)(oc * IC + ic) * 9 + t];
}

__global__ void repack_cx_k(const float* __restrict__ wx, float* __restrict__ o) {
    int i = blockIdx.x * 256 + threadIdx.x;
    if (i >= 131 * 9 * 256) return;
    int g = i & 3; int r = i >> 2; int cc = r & 63; r >>= 6; int t = r % 9; int ic = r / 9;
    int oc = g * 64 + cc;
    o[i] = wx[((size_t)oc * 131 + ic) * 9 + t];
}

__global__ void repack_g0dyn_k(const float* __restrict__ ch0w, const float* __restrict__ cx0w,
                               _Float16* __restrict__ ohi, _Float16* __restrict__ olo) {
    int i = blockIdx.x * 256 + threadIdx.x;
    if (i >= 221184) return;
    int j = i & 7; int lane = (i >> 3) & 63; int mt = (i >> 9) & 15;
    int rest = i >> 13; int kc = rest % 3; int tap = rest / 3;
    int m = mt * 16 + (lane & 15);
    int k = kc * 32 + (lane >> 4) * 8 + j;
    float wv = 0.f;
    if (k < 64)       wv = ch0w[((size_t)m * 64 + k) * 9 + tap];
    else if (k == 64) wv = cx0w[((size_t)m * 131 + 128) * 9 + tap];
    else if (k == 65) wv = cx0w[((size_t)m * 131 + 129) * 9 + tap];
    _Float16 hv = (_Float16)wv;
    ohi[i] = hv;
    olo[i] = (_Float16)(wv - (float)hv);
}

__global__ void repack_g1_k(const float* __restrict__ cx1w, const float* __restrict__ ch1w,
                            _Float16* __restrict__ ohi, _Float16* __restrict__ olo) {
    int i = blockIdx.x * 256 + threadIdx.x;
    if (i >= 294912) return;
    int j = i & 7; int lane = (i >> 3) & 63; int mt = (i >> 9) & 15;
    int rest = i >> 13; int kc = rest & 3; int tap = rest >> 2;
    int m = mt * 16 + (lane & 15);
    int kk = (lane >> 4) * 8 + j;
    float wv;
    if (kc < 2) wv = cx1w[((size_t)m * 64 + kc * 32 + kk) * 9 + tap];
    else        wv = ch1w[((size_t)m * 64 + (kc - 2) * 32 + kk) * 9 + tap];
    _Float16 hv = (_Float16)wv;
    ohi[i] = hv;
    olo[i] = (_Float16)(wv - (float)hv);
}

extern "C" void kernel_launch(void* const* d_in, const int* in_sizes, int n_in,
                              void* d_out, int out_size, void* d_ws, size_t ws_size,
                              hipStream_t stream)
{
    const float* x     = (const float*)d_in[0];
    const int*   fv    = (const int*)  d_in[1];
    const float* c0w   = (const float*)d_in[2];
    const float* c0b   = (const float*)d_in[3];
    const float* c1w   = (const float*)d_in[4];
    const float* c1b   = (const float*)d_in[5];
    const float* cx0w  = (const float*)d_in[6];
    const float* cx0b  = (const float*)d_in[7];
    const float* ch0w  = (const float*)d_in[8];
    const float* ch0b  = (const float*)d_in[9];
    const float* cx1w  = (const float*)d_in[10];
    const float* cx1b  = (const float*)d_in[11];
    const float* ch1w  = (const float*)d_in[12];
    const float* ch1b  = (const float*)d_in[13];
    const float* fcw   = (const float*)d_in[14];
    const float* fcb   = (const float*)d_in[15];
    float* out = (float*)d_out;
    const int n = in_sizes[0] / (256 * 49);

    float* ws   = (float*)d_ws;
    float* w_c0 = ws;                    // 294912
    float* w_c1 = w_c0 + 294912;         // 147456
    float* w_s0 = w_c1 + 147456;         // 301824
    _Float16* g0hi = (_Float16*)(w_s0 + 301824);   // 221184 halves
    _Float16* g0lo = g0hi + 221184;
    _Float16* g1hi = g0lo + 221184;                // 294912 halves
    _Float16* g1lo = g1hi + 294912;

    repack_conv_k <<<(294912 + 255) / 256, 256, 0, stream>>>(c0w, w_c0, 256, 128);
    repack_conv_k <<<(147456 + 255) / 256, 256, 0, stream>>>(c1w, w_c1, 128, 128);
    repack_cx_k   <<<(301824 + 255) / 256, 256, 0, stream>>>(cx0w, w_s0);
    repack_g0dyn_k<<<(221184 + 255) / 256, 256, 0, stream>>>(ch0w, cx0w, g0hi, g0lo);
    repack_g1_k   <<<(294912 + 255) / 256, 256, 0, stream>>>(cx1w, ch1w, g1hi, g1lo);

    (void)hipFuncSetAttribute((const void*)poly_rnn_main,
                              hipFuncAttributeMaxDynamicSharedMemorySize, SHF * 4);
    poly_rnn_main<<<n / 2, 512, SHF * 4, stream>>>(x, fv, w_c0, c0b, w_c1, c1b,
                                                   w_s0, cx0b, ch0b,
                                                   g0hi, g0lo, g1hi, g1lo,
                                                   cx1b, ch1b, fcw, fcb, out);
}

// Round 4
// 5863.513 us; speedup vs baseline: 18.2788x; 1.7554x over previous
//
#include <hip/hip_runtime.h>
#include <hip/hip_fp16.h>

typedef float f32x4 __attribute__((ext_vector_type(4)));
typedef _Float16 f16x8 __attribute__((ext_vector_type(8)));
typedef _Float16 f16x4 __attribute__((ext_vector_type(4)));

// ---------------- LDS byte map (regions alias across phases) ----------------
// phase A: XP (x f16 planes [49][264]) hi@0 lo@25872 (ends 51744)
//          XF (conv0 out [49][136])    hi@51744 lo@65072 (ends 78400)
//          XF2 (conv1 out [49][136])   hi@0 lo@13328  (aliases XP, XP dead)
// phase B: PL (planes [49][168]: h0 0..63, vp2 64, vp1 65, zero 66..95,
//              h1 96..159, pad)        hi@0 lo@16464 (ends 32928)
//          H1F (h1 flat [3136], k=p*64+ch) hi@32928 lo@39200 (ends 45472)
//          FCP fc partials [4][64] f32 @45472 ; PRD pred int @46496
// Z512: 512 B of zeros @78400 (never written after init) -> OOW fallback
#define XP_HI  0
#define XP_LO  25872
#define XF_HI  51744
#define XF_LO  65072
#define XF2_HI 0
#define XF2_LO 13328
#define PL_HI  0
#define PL_LO  16464
#define H1F_HI 32928
#define H1F_LO 39200
#define FCP    45472
#define PRD    46496
#define Z512   78400
#define LDSB   78912

__device__ __forceinline__ float sigmoidf_(float v) { return 1.0f / (1.0f + expf(-v)); }

// shifted-window conv GEMM: acc[ii][n] += sum_taps A(tap,kc,mi) * B(window(col,tap),kc)
// split precision: Al*Bh + Ah*Bl + Ah*Bh, fp32 accumulate.
template <int NKC, int NMI>
__device__ __forceinline__ void conv_mfma_run(
    const char* __restrict__ SHb, int hiB, int loB, int pstr2,
    const int (&kofs)[NKC], int q16,
    const _Float16* __restrict__ ghi, const _Float16* __restrict__ glo,
    int NMF, int miBase, int miStep,
    const int (&okc)[4], const int (&py0)[4], const int (&px0)[4],
    f32x4 (&acc)[NMI][4], int lane)
{
    for (int dy = -1; dy <= 1; ++dy)
    for (int dx = -1; dx <= 1; ++dx) {
        const int tap = (dy + 1) * 3 + (dx + 1);
        int bh[4], bl[4];
        #pragma unroll
        for (int n = 0; n < 4; ++n) {
            int py = py0[n] + dy, px = px0[n] + dx;
            bool ok = okc[n] && ((unsigned)py < 7u) && ((unsigned)px < 7u);
            int qb = (py * 7 + px) * pstr2;
            bh[n] = ok ? hiB + qb : Z512;     // Z512 + kof stays inside zero block
            bl[n] = ok ? loB + qb : Z512;
        }
        #pragma unroll
        for (int kc = 0; kc < NKC; ++kc) {
            const int kof = kofs[kc] + q16;
            f16x8 Bh[4], Bl[4];
            #pragma unroll
            for (int n = 0; n < 4; ++n) {
                Bh[n] = *(const f16x8*)(SHb + bh[n] + kof);
                Bl[n] = *(const f16x8*)(SHb + bl[n] + kof);
            }
            #pragma unroll
            for (int ii = 0; ii < NMI; ++ii) {
                int frag = (((tap * NKC + kc) * NMF + (miBase + ii * miStep)) << 9) + lane * 8;
                f16x8 Ah = *(const f16x8*)(ghi + frag);
                f16x8 Al = *(const f16x8*)(glo + frag);
                #pragma unroll
                for (int n = 0; n < 4; ++n) {
                    acc[ii][n] = __builtin_amdgcn_mfma_f32_16x16x32_f16(Al, Bh[n], acc[ii][n], 0, 0, 0);
                    acc[ii][n] = __builtin_amdgcn_mfma_f32_16x16x32_f16(Ah, Bl[n], acc[ii][n], 0, 0, 0);
                    acc[ii][n] = __builtin_amdgcn_mfma_f32_16x16x32_f16(Ah, Bh[n], acc[ii][n], 0, 0, 0);
                }
            }
        }
    }
}

extern "C" __global__ __launch_bounds__(256, 2)
void poly_fused(const float* __restrict__ x, const int* __restrict__ firstv,
                const float* __restrict__ b_c0, const float* __restrict__ b_c1,
                const float* __restrict__ cx0b, const float* __restrict__ ch0b,
                const float* __restrict__ cx1b, const float* __restrict__ ch1b,
                const float* __restrict__ fcb,
                const _Float16* __restrict__ c0hi, const _Float16* __restrict__ c0lo,
                const _Float16* __restrict__ c1hi, const _Float16* __restrict__ c1lo,
                const _Float16* __restrict__ cshi, const _Float16* __restrict__ cslo,
                const _Float16* __restrict__ g0hi, const _Float16* __restrict__ g0lo,
                const _Float16* __restrict__ g1hi, const _Float16* __restrict__ g1lo,
                const _Float16* __restrict__ fchi, const _Float16* __restrict__ fclo,
                const float* __restrict__ wv1,
                float* __restrict__ out)
{
    extern __shared__ char SHC[];
    float* SHf = (float*)SHC;
    const int tid = threadIdx.x, s = blockIdx.x;
    const int lane = tid & 63, w = tid >> 6;
    const int q = lane >> 4, l15 = lane & 15, q16 = q * 16;

    for (int i = tid; i < LDSB / 4; i += 256) SHf[i] = 0.f;
    __syncthreads();

    // per-lane column geometry (col = n*16 + l15, 49 live pixels)
    int okc[4], py0[4], px0[4];
    #pragma unroll
    for (int n = 0; n < 4; ++n) {
        int col = n * 16 + l15;
        okc[n] = col < 49;
        int p = okc[n] ? col : 0;
        py0[n] = p / 7; px0[n] = p % 7;
    }

    // ============ PHASE A ============
    // stage x -> XP f16 hi/lo planes [49][264]
    const float* xs = x + (size_t)s * 12544;
    for (int e = tid; e < 12544; e += 256) {
        int ch = e / 49, p = e - ch * 49;
        float v = xs[e];
        _Float16 hv = (_Float16)v;
        *(_Float16*)(SHC + XP_HI + p * 528 + ch * 2) = hv;
        *(_Float16*)(SHC + XP_LO + p * 528 + ch * 2) = (_Float16)(v - (float)hv);
    }
    __syncthreads();

    const int kofs8[8] = {0, 64, 128, 192, 256, 320, 384, 448};
    const int kofs4[4] = {0, 64, 128, 192};

    // conv0: M=128 (8 mfrags, wave owns w*2, w*2+1), K=256
    {
        f32x4 acc2[2][4];
        #pragma unroll
        for (int ii = 0; ii < 2; ++ii)
            #pragma unroll
            for (int n = 0; n < 4; ++n) acc2[ii][n] = (f32x4){0.f, 0.f, 0.f, 0.f};
        conv_mfma_run<8, 2>(SHC, XP_HI, XP_LO, 528, kofs8, q16, c0hi, c0lo,
                            8, w * 2, 1, okc, py0, px0, acc2, lane);
        #pragma unroll
        for (int ii = 0; ii < 2; ++ii) {
            f32x4 bb = *(const f32x4*)(b_c0 + (w * 2 + ii) * 16 + q * 4);
            int chB = ((w * 2 + ii) * 16 + q * 4) * 2;
            #pragma unroll
            for (int n = 0; n < 4; ++n) if (okc[n]) {
                int p = n * 16 + l15;
                f16x4 h, l;
                #pragma unroll
                for (int r = 0; r < 4; ++r) {
                    float v = fmaxf(acc2[ii][n][r] + bb[r], 0.f);
                    _Float16 hv = (_Float16)v;
                    h[r] = hv; l[r] = (_Float16)(v - (float)hv);
                }
                *(f16x4*)(SHC + XF_HI + p * 272 + chB) = h;
                *(f16x4*)(SHC + XF_LO + p * 272 + chB) = l;
            }
        }
    }
    __syncthreads();   // XF visible, XP dead

    // conv1: M=128, K=128, XF -> XF2 (aliases XP)
    {
        f32x4 acc2[2][4];
        #pragma unroll
        for (int ii = 0; ii < 2; ++ii)
            #pragma unroll
            for (int n = 0; n < 4; ++n) acc2[ii][n] = (f32x4){0.f, 0.f, 0.f, 0.f};
        conv_mfma_run<4, 2>(SHC, XF_HI, XF_LO, 272, kofs4, q16, c1hi, c1lo,
                            8, w * 2, 1, okc, py0, px0, acc2, lane);
        #pragma unroll
        for (int ii = 0; ii < 2; ++ii) {
            f32x4 bb = *(const f32x4*)(b_c1 + (w * 2 + ii) * 16 + q * 4);
            int chB = ((w * 2 + ii) * 16 + q * 4) * 2;
            #pragma unroll
            for (int n = 0; n < 4; ++n) if (okc[n]) {
                int p = n * 16 + l15;
                f16x4 h, l;
                #pragma unroll
                for (int r = 0; r < 4; ++r) {
                    float v = fmaxf(acc2[ii][n][r] + bb[r], 0.f);
                    _Float16 hv = (_Float16)v;
                    h[r] = hv; l[r] = (_Float16)(v - (float)hv);
                }
                *(f16x4*)(SHC + XF2_HI + p * 272 + chB) = h;
                *(f16x4*)(SHC + XF2_LO + p * 272 + chB) = l;
            }
        }
    }
    __syncthreads();   // XF2 visible

    // static gates: M=256 (16 mfrags, wave owns g*4+w), K=128 (x_feat)
    f32x4 st[4][4];
    #pragma unroll
    for (int g = 0; g < 4; ++g)
        #pragma unroll
        for (int n = 0; n < 4; ++n) st[g][n] = (f32x4){0.f, 0.f, 0.f, 0.f};
    conv_mfma_run<4, 4>(SHC, XF2_HI, XF2_LO, 272, kofs4, q16, cshi, cslo,
                        16, w, 4, okc, py0, px0, st, lane);
    const int fv = firstv[s];
    const int fy = fv / 7, fx = fv % 7;
    #pragma unroll
    for (int g = 0; g < 4; ++g) {
        int m0 = g * 64 + w * 16 + q * 4;
        f32x4 ba = *(const f32x4*)(cx0b + m0);
        f32x4 bh2 = *(const f32x4*)(ch0b + m0);
        #pragma unroll
        for (int n = 0; n < 4; ++n) {
            st[g][n] += ba + bh2;
            int dy = fy - py0[n], dx = fx - px0[n];
            if (okc[n] && dy >= -1 && dy <= 1 && dx >= -1 && dx <= 1) {
                int tap = (dy + 1) * 3 + (dx + 1);
                st[g][n] += *(const f32x4*)(wv1 + tap * 256 + m0);
            }
        }
    }
    __syncthreads();   // XF2 dead

    // zero phase-B region (PL + H1F + FCP + PRD = bytes 0..46500)
    for (int i = tid; i < 11625; i += 256) SHf[i] = 0.f;
    __syncthreads();
    if (tid == 0) *(_Float16*)(SHC + PL_HI + fv * 336 + 65 * 2) = (_Float16)1.f;  // vp1 = v_first

    // biases for layer 1
    float b1[4][4];
    #pragma unroll
    for (int g = 0; g < 4; ++g) {
        int m0 = g * 64 + w * 16 + q * 4;
        f32x4 ba = *(const f32x4*)(cx1b + m0);
        f32x4 bb = *(const f32x4*)(ch1b + m0);
        #pragma unroll
        for (int r = 0; r < 4; ++r) b1[g][r] = ba[r] + bb[r];
    }

    float c0s[4][4], c1s[4][4];
    #pragma unroll
    for (int n = 0; n < 4; ++n)
        #pragma unroll
        for (int r = 0; r < 4; ++r) { c0s[n][r] = 0.f; c1s[n][r] = 0.f; }

    float* outS = out + (size_t)s * 450;
    const int kofs3[3] = {0, 64, 128};
    const int kofsL1[4] = {0, 64, 192, 256};

    // ============ PHASE B: 9 recurrent steps ============
    for (int t = 0; t < 9; ++t) {
        __syncthreads();                       // planes/v consistent
        f32x4 acc[4][4];
        #pragma unroll
        for (int g = 0; g < 4; ++g)
            #pragma unroll
            for (int n = 0; n < 4; ++n) acc[g][n] = st[g][n];
        conv_mfma_run<3, 4>(SHC, PL_HI, PL_LO, 336, kofs3, q16, g0hi, g0lo,
                            16, w, 4, okc, py0, px0, acc, lane);
        __syncthreads();                       // all done reading h0
        {   // L0 LSTM epilogue, fully in-lane
            int chB = (w * 16 + q * 4) * 2;
            #pragma unroll
            for (int n = 0; n < 4; ++n) if (okc[n]) {
                int p = n * 16 + l15;
                f16x4 h, l;
                #pragma unroll
                for (int r = 0; r < 4; ++r) {
                    float ig = sigmoidf_(acc[0][n][r]);
                    float fg = sigmoidf_(acc[1][n][r]);
                    float gg = tanhf(acc[2][n][r]);
                    float og = sigmoidf_(acc[3][n][r]);
                    float cy = fg * c0s[n][r] + ig * gg;
                    c0s[n][r] = cy;
                    float hy = og * tanhf(cy);
                    _Float16 hv = (_Float16)hy;
                    h[r] = hv; l[r] = (_Float16)(hy - (float)hv);
                }
                *(f16x4*)(SHC + PL_HI + p * 336 + chB) = h;
                *(f16x4*)(SHC + PL_LO + p * 336 + chB) = l;
            }
        }
        __syncthreads();                       // h0 new visible
        #pragma unroll
        for (int g = 0; g < 4; ++g)
            #pragma unroll
            for (int n = 0; n < 4; ++n) {
                acc[g][n][0] = b1[g][0]; acc[g][n][1] = b1[g][1];
                acc[g][n][2] = b1[g][2]; acc[g][n][3] = b1[g][3];
            }
        conv_mfma_run<4, 4>(SHC, PL_HI, PL_LO, 336, kofsL1, q16, g1hi, g1lo,
                            16, w, 4, okc, py0, px0, acc, lane);
        __syncthreads();                       // all done reading h1 old
        {   // L1 LSTM epilogue
            int chB = ((96 + w * 16 + q * 4)) * 2;
            int chF = (w * 16 + q * 4) * 2;
            #pragma unroll
            for (int n = 0; n < 4; ++n) if (okc[n]) {
                int p = n * 16 + l15;
                f16x4 h, l;
                #pragma unroll
                for (int r = 0; r < 4; ++r) {
                    float ig = sigmoidf_(acc[0][n][r]);
                    float fg = sigmoidf_(acc[1][n][r]);
                    float gg = tanhf(acc[2][n][r]);
                    float og = sigmoidf_(acc[3][n][r]);
                    float cy = fg * c1s[n][r] + ig * gg;
                    c1s[n][r] = cy;
                    float hy = og * tanhf(cy);
                    _Float16 hv = (_Float16)hy;
                    h[r] = hv; l[r] = (_Float16)(hy - (float)hv);
                }
                *(f16x4*)(SHC + PL_HI + p * 336 + chB) = h;
                *(f16x4*)(SHC + PL_LO + p * 336 + chB) = l;
                *(f16x4*)(SHC + H1F_HI + p * 128 + chF) = h;
                *(f16x4*)(SHC + H1F_LO + p * 128 + chF) = l;
            }
        }
        __syncthreads();                       // h1flat visible
        {   // fc via MFMA: M=64 (50 live), K=3136 flat, col 0 live
            f32x4 afc[4];
            #pragma unroll
            for (int mi = 0; mi < 4; ++mi) afc[mi] = (f32x4){0.f, 0.f, 0.f, 0.f};
            int kc0 = (w < 3) ? w * 25 : 74;
            int kcN = (w < 2) ? 25 : 24;
            for (int kc = 0; kc < kcN; ++kc) {
                int koff = (kc0 + kc) * 64 + q16;
                int aH = (l15 == 0) ? (H1F_HI + koff) : Z512;
                int aL = (l15 == 0) ? (H1F_LO + koff) : Z512;
                f16x8 Bh = *(const f16x8*)(SHC + aH);
                f16x8 Bl = *(const f16x8*)(SHC + aL);
                #pragma unroll
                for (int mi = 0; mi < 4; ++mi) {
                    int frag = (((kc0 + kc) * 4 + mi) << 9) + lane * 8;
                    f16x8 Ah = *(const f16x8*)(fchi + frag);
                    f16x8 Al = *(const f16x8*)(fclo + frag);
                    afc[mi] = __builtin_amdgcn_mfma_f32_16x16x32_f16(Al, Bh, afc[mi], 0, 0, 0);
                    afc[mi] = __builtin_amdgcn_mfma_f32_16x16x32_f16(Ah, Bl, afc[mi], 0, 0, 0);
                    afc[mi] = __builtin_amdgcn_mfma_f32_16x16x32_f16(Ah, Bh, afc[mi], 0, 0, 0);
                }
            }
            if (l15 == 0) {
                #pragma unroll
                for (int mi = 0; mi < 4; ++mi)
                    *(f32x4*)(SHC + FCP + w * 256 + mi * 64 + q16) = afc[mi];
            }
        }
        __syncthreads();                       // fc partials visible
        if (tid < 64) {
            int c = tid;
            const float* fp = (const float*)(SHC + FCP);
            float lg = fp[c] + fp[64 + c] + fp[128 + c] + fp[192 + c];
            float v = -3.4e38f;
            if (c < 50) { lg += fcb[c]; outS[t * 50 + c] = lg; v = lg; }
            int idx = c;
            #pragma unroll
            for (int off = 1; off < 64; off <<= 1) {
                float ov = __shfl_xor(v, off, 64);
                int   oi = __shfl_xor(idx, off, 64);
                if (ov > v || (ov == v && oi < idx)) { v = ov; idx = oi; }
            }
            if (c == 0) *(int*)(SHC + PRD) = idx;
        }
        __syncthreads();                       // pred visible
        if (tid < 49) {
            int pred = *(const int*)(SHC + PRD);
            _Float16* Hp = (_Float16*)(SHC + PL_HI + tid * 336);
            Hp[64] = Hp[65];                                   // vp2 <- vp1
            Hp[65] = (_Float16)((tid == pred) ? 1.f : 0.f);    // vp1 <- one-hot(pred)
        }
    }
}

// ================= weight repack kernels =================
// generic OIHW conv weights -> A fragments [tap][kc][mi][lane][8], hi/lo split
__global__ void repack_frags_k(const float* __restrict__ w, _Float16* __restrict__ ohi,
                               _Float16* __restrict__ olo, int ICS, int KMAX,
                               int NKC, int NMF, int total) {
    int i = blockIdx.x * 256 + threadIdx.x;
    if (i >= total) return;
    int j = i & 7, lane = (i >> 3) & 63;
    int rest = i >> 9;
    int mi = rest % NMF; rest /= NMF;
    int kc = rest % NKC; int tap = rest / NKC;
    int m = mi * 16 + (lane & 15);
    int k = kc * 32 + ((lane >> 4) & 3) * 8 + j;
    float v = (k < KMAX) ? w[((size_t)m * ICS + k) * 9 + tap] : 0.f;
    _Float16 hv = (_Float16)v;
    ohi[i] = hv; olo[i] = (_Float16)(v - (float)hv);
}

__global__ void repack_g0dyn_k(const float* __restrict__ ch0w, const float* __restrict__ cx0w,
                               _Float16* __restrict__ ohi, _Float16* __restrict__ olo) {
    int i = blockIdx.x * 256 + threadIdx.x;
    if (i >= 221184) return;
    int j = i & 7; int lane = (i >> 3) & 63; int mt = (i >> 9) & 15;
    int rest = i >> 13; int kc = rest % 3; int tap = rest / 3;
    int m = mt * 16 + (lane & 15);
    int k = kc * 32 + (lane >> 4) * 8 + j;
    float wv = 0.f;
    if (k < 64)       wv = ch0w[((size_t)m * 64 + k) * 9 + tap];
    else if (k == 64) wv = cx0w[((size_t)m * 131 + 128) * 9 + tap];
    else if (k == 65) wv = cx0w[((size_t)m * 131 + 129) * 9 + tap];
    _Float16 hv = (_Float16)wv;
    ohi[i] = hv; olo[i] = (_Float16)(wv - (float)hv);
}

__global__ void repack_g1_k(const float* __restrict__ cx1w, const float* __restrict__ ch1w,
                            _Float16* __restrict__ ohi, _Float16* __restrict__ olo) {
    int i = blockIdx.x * 256 + threadIdx.x;
    if (i >= 294912) return;
    int j = i & 7; int lane = (i >> 3) & 63; int mt = (i >> 9) & 15;
    int rest = i >> 13; int kc = rest & 3; int tap = rest >> 2;
    int m = mt * 16 + (lane & 15);
    int kk = (lane >> 4) * 8 + j;
    float wv;
    if (kc < 2) wv = cx1w[((size_t)m * 64 + kc * 32 + kk) * 9 + tap];
    else        wv = ch1w[((size_t)m * 64 + (kc - 2) * 32 + kk) * 9 + tap];
    _Float16 hv = (_Float16)wv;
    ohi[i] = hv; olo[i] = (_Float16)(wv - (float)hv);
}

// fc weights [50][3136] -> frags [kc 98][mi 4][lane][8], k = p*64+ch, m = class
__global__ void repack_fc_k(const float* __restrict__ fcw, _Float16* __restrict__ ohi,
                            _Float16* __restrict__ olo) {
    int i = blockIdx.x * 256 + threadIdx.x;
    if (i >= 200704) return;
    int j = i & 7, lane = (i >> 3) & 63;
    int rest = i >> 9;
    int mi = rest & 3, kc = rest >> 2;
    int cls = mi * 16 + (lane & 15);
    int k = kc * 32 + ((lane >> 4) & 3) * 8 + j;
    int ch = k & 63, p = k >> 6;
    float v = (cls < 50) ? fcw[(size_t)cls * 3136 + ch * 49 + p] : 0.f;
    _Float16 hv = (_Float16)v;
    ohi[i] = hv; olo[i] = (_Float16)(v - (float)hv);
}

__global__ void repack_wv1_k(const float* __restrict__ cx0w, float* __restrict__ o) {
    int i = blockIdx.x * 256 + threadIdx.x;
    if (i >= 2304) return;
    int tap = i / 256, m = i % 256;
    o[i] = cx0w[((size_t)m * 131 + 130) * 9 + tap];
}

extern "C" void kernel_launch(void* const* d_in, const int* in_sizes, int n_in,
                              void* d_out, int out_size, void* d_ws, size_t ws_size,
                              hipStream_t stream)
{
    const float* x     = (const float*)d_in[0];
    const int*   fv    = (const int*)  d_in[1];
    const float* c0w   = (const float*)d_in[2];
    const float* c0b   = (const float*)d_in[3];
    const float* c1w   = (const float*)d_in[4];
    const float* c1b   = (const float*)d_in[5];
    const float* cx0w  = (const float*)d_in[6];
    const float* cx0b  = (const float*)d_in[7];
    const float* ch0w  = (const float*)d_in[8];
    const float* ch0b  = (const float*)d_in[9];
    const float* cx1w  = (const float*)d_in[10];
    const float* cx1b  = (const float*)d_in[11];
    const float* ch1w  = (const float*)d_in[12];
    const float* ch1b  = (const float*)d_in[13];
    const float* fcw   = (const float*)d_in[14];
    const float* fcb   = (const float*)d_in[15];
    float* out = (float*)d_out;
    const int n = in_sizes[0] / 12544;

    _Float16* h = (_Float16*)d_ws;
    _Float16* g0hi = h;                  // 221184
    _Float16* g0lo = g0hi + 221184;
    _Float16* g1hi = g0lo + 221184;      // 294912
    _Float16* g1lo = g1hi + 294912;
    _Float16* c0hi = g1lo + 294912;      // 294912
    _Float16* c0lo = c0hi + 294912;
    _Float16* c1hi = c0lo + 294912;      // 147456
    _Float16* c1lo = c1hi + 147456;
    _Float16* cshi = c1lo + 147456;      // 294912
    _Float16* cslo = cshi + 294912;
    _Float16* fchi = cslo + 294912;      // 200704
    _Float16* fclo = fchi + 200704;
    float*    wv1  = (float*)(fclo + 200704);   // 2304 f32

    repack_g0dyn_k<<<(221184 + 255) / 256, 256, 0, stream>>>(ch0w, cx0w, g0hi, g0lo);
    repack_g1_k   <<<(294912 + 255) / 256, 256, 0, stream>>>(cx1w, ch1w, g1hi, g1lo);
    repack_frags_k<<<(294912 + 255) / 256, 256, 0, stream>>>(c0w, c0hi, c0lo, 256, 256, 8, 8, 294912);
    repack_frags_k<<<(147456 + 255) / 256, 256, 0, stream>>>(c1w, c1hi, c1lo, 128, 128, 4, 8, 147456);
    repack_frags_k<<<(294912 + 255) / 256, 256, 0, stream>>>(cx0w, cshi, cslo, 131, 128, 4, 16, 294912);
    repack_fc_k   <<<(200704 + 255) / 256, 256, 0, stream>>>(fcw, fchi, fclo);
    repack_wv1_k  <<<(2304 + 255) / 256, 256, 0, stream>>>(cx0w, wv1);

    (void)hipFuncSetAttribute((const void*)poly_fused,
                              hipFuncAttributeMaxDynamicSharedMemorySize, LDSB);
    poly_fused<<<n, 256, LDSB, stream>>>(x, fv, c0b, c1b, cx0b, ch0b, cx1b, ch1b, fcb,
                                         c0hi, c0lo, c1hi, c1lo, cshi, cslo,
                                         g0hi, g0lo, g1hi, g1lo, fchi, fclo, wv1, out);
}